// Round 1
// baseline (14887.923 us; speedup 1.0000x reference)
//
#include <hip/hip_runtime.h>
#include <stdint.h>

typedef unsigned short u16;
typedef unsigned int   u32;
typedef __bf16 bf16x8 __attribute__((ext_vector_type(8)));
typedef float  f32x4  __attribute__((ext_vector_type(4)));
typedef u16    u16x8  __attribute__((ext_vector_type(8)));

#define TBROWS 32704   // 511 * 64 valid (t,b) rows

__device__ __forceinline__ u16 f2bf(float f) {
  union { float f; u32 u; } v; v.f = f;
  u32 r = v.u + 0x7FFFu + ((v.u >> 16) & 1u);   // RNE
  return (u16)(r >> 16);
}
__device__ __forceinline__ float bf2f(u16 h) {
  union { u32 u; float f; } v; v.u = ((u32)h) << 16;
  return v.f;
}
__device__ __forceinline__ float fsigmoid(float x) {
  return 1.0f / (1.0f + exp2f(-1.44269504f * x));
}
__device__ __forceinline__ float ftanh(float x) {
  return 2.0f / (1.0f + exp2f(-2.88539008f * x)) - 1.0f;
}

// ---------------- conversions ----------------

// x f32 [64][512][1024] -> bf16 same layout
__global__ __launch_bounds__(256) void conv_x(const float* __restrict__ x,
                                              u16* __restrict__ xb) {
  const int n4 = (64 * 512 * 1024) / 4;
  const float4* xv = (const float4*)x;
  for (int i = blockIdx.x * 256 + threadIdx.x; i < n4; i += 4096 * 256) {
    float4 v = xv[i];
    uint2 o;
    o.x = (u32)f2bf(v.x) | ((u32)f2bf(v.y) << 16);
    o.y = (u32)f2bf(v.z) | ((u32)f2bf(v.w) << 16);
    *(uint2*)(xb + (size_t)i * 4) = o;
  }
}

// Build UbT bf16 [4096][1024]: UbT[n][k] = U_g[k][hc], n = hc*4 + g (gate-interleaved)
__global__ __launch_bounds__(256) void conv_u(const float* __restrict__ U0,
                                              const float* __restrict__ U1,
                                              const float* __restrict__ U2,
                                              const float* __restrict__ U3,
                                              u16* __restrict__ UbT) {
  __shared__ float tile[64][65];
  const int bid = blockIdx.x;
  const int g = bid >> 8, kt = (bid >> 4) & 15, ht = bid & 15;
  const float* U = (g == 0) ? U0 : (g == 1) ? U1 : (g == 2) ? U2 : U3;
  const int t = threadIdx.x;
  const int c = t & 63, r0 = t >> 6;
#pragma unroll
  for (int rr = 0; rr < 64; rr += 4)
    tile[rr + r0][c] = U[(size_t)(kt * 64 + rr + r0) * 1024 + ht * 64 + c];
  __syncthreads();
  const int hcl = t >> 2, ks = t & 3;
  const int n = (ht * 64 + hcl) * 4 + g;
  u16x8 o0, o1;
#pragma unroll
  for (int ii = 0; ii < 8; ++ii) o0[ii] = f2bf(tile[ks * 16 + ii][hcl]);
#pragma unroll
  for (int ii = 0; ii < 8; ++ii) o1[ii] = f2bf(tile[ks * 16 + 8 + ii][hcl]);
  size_t base = (size_t)n * 1024 + kt * 64 + ks * 16;
  *(u16x8*)(UbT + base) = o0;
  *(u16x8*)(UbT + base + 8) = o1;
}

// bb f32 [4096] gate-interleaved: bb[hc*4+g] = b_g[hc]
__global__ __launch_bounds__(256) void conv_b(const float* __restrict__ b0,
                                              const float* __restrict__ b1,
                                              const float* __restrict__ b2,
                                              const float* __restrict__ b3,
                                              float* __restrict__ bb) {
  int n = blockIdx.x * 256 + threadIdx.x;
  if (n < 4096) {
    int g = n & 3, hc = n >> 2;
    const float* B = (g == 0) ? b0 : (g == 1) ? b1 : (g == 2) ? b2 : b3;
    bb[n] = B[hc];
  }
}

// zero h state buffer 0 and flags (re-run every call -> replay-safe)
__global__ __launch_bounds__(256) void init_ws(u16* hbuf, int* flags) {
  int i = blockIdx.x * 256 + threadIdx.x;     // 16384 threads
  if (i < 256) flags[i] = 0;
  u32* hz = (u32*)hbuf;
  for (int k = i; k < 32768; k += 16384) hz[k] = 0;
}

// ---------------- phase 1: x_proj GEMM ----------------
// Computes xp[hc][tb][g] = sum_k UbT[hc*4+g][k] * xb[tb][k] + bb  (bf16 out)
// A = UbT (M=4096), B = x rows (N=32704). m97 structure: 128x128 tile, BK=32.
__global__ __launch_bounds__(256, 2) void gemm_xproj(const u16* __restrict__ xb,
                                                     const u16* __restrict__ UbT,
                                                     const float* __restrict__ bb,
                                                     u16* __restrict__ xp) {
  __shared__ __align__(16) u16 As[128 * 32];
  __shared__ __align__(16) u16 Bs[128 * 32];
  const int tid = threadIdx.x;
  const int lane = tid & 63, w = tid >> 6;
  const int q = lane >> 4, r15 = lane & 15;
  const int nt = blockIdx.x & 31;        // M (n) tile
  const int tt = blockIdx.x >> 5;        // N (tb) tile
  const int n_base = nt * 128;
  const long long tb_base = (long long)tt * 128;
  const int mh = w & 1, nh = w >> 1;

  f32x4 acc[4][4];
#pragma unroll
  for (int a = 0; a < 4; ++a)
#pragma unroll
    for (int b2 = 0; b2 < 4; ++b2) acc[a][b2] = (f32x4){0.f, 0.f, 0.f, 0.f};

#pragma unroll 1
  for (int kb = 0; kb < 32; ++kb) {
    __syncthreads();
    const int k0 = kb * 32;
#pragma unroll
    for (int call = 0; call < 2; ++call) {
      const int chunk = call * 256 + w * 64 + lane;
      const int row = chunk >> 2, q4 = chunk & 3;
      const u16* ga = UbT + (size_t)(n_base + row) * 1024 + k0 + q4 * 8;
      __builtin_amdgcn_global_load_lds(
          (const __attribute__((address_space(1))) void*)ga,
          (__attribute__((address_space(3))) void*)(As + (call * 256 + w * 64) * 8),
          16, 0, 0);
      long long tbr = tb_base + row;
      if (tbr > TBROWS - 1) tbr = TBROWS - 1;
      const int xbrow = ((int)tbr & 63) * 512 + ((int)tbr >> 6);  // (b,t) -> x row
      const u16* gb = xb + (size_t)xbrow * 1024 + k0 + q4 * 8;
      __builtin_amdgcn_global_load_lds(
          (const __attribute__((address_space(1))) void*)gb,
          (__attribute__((address_space(3))) void*)(Bs + (call * 256 + w * 64) * 8),
          16, 0, 0);
    }
    __syncthreads();
    bf16x8 af[4], bfr[4];
#pragma unroll
    for (int m = 0; m < 4; ++m)
      af[m] = *(const bf16x8*)(As + ((mh * 64 + m * 16 + r15) * 32 + q * 8));
#pragma unroll
    for (int n2 = 0; n2 < 4; ++n2)
      bfr[n2] = *(const bf16x8*)(Bs + ((nh * 64 + n2 * 16 + r15) * 32 + q * 8));
#pragma unroll
    for (int m = 0; m < 4; ++m)
#pragma unroll
      for (int n2 = 0; n2 < 4; ++n2)
        acc[m][n2] = __builtin_amdgcn_mfma_f32_16x16x32_bf16(af[m], bfr[n2],
                                                             acc[m][n2], 0, 0, 0);
  }
  // epilogue: lane's 4 C-regs = 4 consecutive n = 4 gates of one hc -> 8B store
#pragma unroll
  for (int m = 0; m < 4; ++m) {
    const int nrow = n_base + mh * 64 + m * 16 + q * 4;
    const float4 bias = *(const float4*)(bb + nrow);
    const long long hcb = (long long)(nrow >> 2) * TBROWS;
#pragma unroll
    for (int n2 = 0; n2 < 4; ++n2) {
      const long long tb = tb_base + nh * 64 + n2 * 16 + r15;
      if (tb < TBROWS) {
        const f32x4 v = acc[m][n2];
        uint2 pk;
        pk.x = (u32)f2bf(v[0] + bias.x) | ((u32)f2bf(v[1] + bias.y) << 16);
        pk.y = (u32)f2bf(v[2] + bias.z) | ((u32)f2bf(v[3] + bias.w) << 16);
        *(uint2*)(xp + (hcb + tb) * 4) = pk;
      }
    }
  }
}

// ---------------- phase 2: persistent recurrence ----------------
// 256 blocks = 64 hc-blocks x 4 independent batch-quarters; 4 waves/block.
// V^T fragments register-resident (128 VGPR/lane). h double-buffered in ws,
// layout [hcblk][b][hcl16] bf16; coherent via agent-scope atomics + flags.
__global__ __launch_bounds__(256, 1) void lstm_rec(
    const float* __restrict__ V0, const float* __restrict__ V1,
    const float* __restrict__ V2, const float* __restrict__ V3,
    const u16* __restrict__ xp, u16* hbuf, int* flags, float* __restrict__ out) {
  const int tid = threadIdx.x;
  const int lane = tid & 63;
  const int w = tid >> 6;          // wave = M-tile (zrows w*16..w*16+16)
  const int q = lane >> 4;
  const int r15 = lane & 15;
  const int j = blockIdx.x & 63;   // hc block (16 hidden units)
  const int bq = blockIdx.x >> 6;  // batch quarter (16 batches)
  const int b = bq * 16 + r15;

  // ---- A fragments: zrow = w*16 + r15 -> (hc, gate); k = kk*32 + q*8 + jj
  const int gA = r15 & 3;
  const int hcA = j * 16 + w * 4 + (r15 >> 2);
  const float* Vm = (gA == 0) ? V0 : (gA == 1) ? V1 : (gA == 2) ? V2 : V3;
  const float* Vcol = Vm + hcA;
  bf16x8 areg[32];
#pragma unroll
  for (int kk = 0; kk < 32; ++kk) {
    union { bf16x8 v; u16 s[8]; } au;
    const int k0 = kk * 32 + q * 8;
#pragma unroll
    for (int jj = 0; jj < 8; ++jj)
      au.s[jj] = f2bf(Vcol[(size_t)(k0 + jj) * 1024]);
    areg[kk] = au.v;
  }

  const int hcl = w * 4 + q;           // C-layout: lane owns (b, hc), 4 gates in regs
  const int hc = j * 16 + hcl;
  const long long xpbase = (long long)hc * TBROWS * 4;
  const int boff = b * 8 + (q & 1) * 4;   // u32 offset within a k16-slab
  float c = 0.0f;

#pragma unroll 1
  for (int it = 0; it < 512; ++it) {
    if (it > 0) {
      if (tid < 64) {
        const int* fp = flags + bq * 64 + tid;
        while (__hip_atomic_load(fp, __ATOMIC_RELAXED, __HIP_MEMORY_SCOPE_AGENT) < it) {}
      }
      __syncthreads();
    }
    const u16* hp = hbuf + (size_t)(it & 1) * 65536;
    u16* hn = hbuf + (size_t)((it + 1) & 1) * 65536;

    const long long tb = (long long)(it < 511 ? it : 510) * 64 + b;
    const uint2 xpv = *(const uint2*)(xp + xpbase + tb * 4);  // 4 gates, bf16

    f32x4 acc0 = {0.f, 0.f, 0.f, 0.f}, acc1 = {0.f, 0.f, 0.f, 0.f};
    const u32* hp32 = (const u32*)hp;
#pragma unroll 8
    for (int kk = 0; kk < 32; ++kk) {
      const u32* p = hp32 + (size_t)(kk * 2 + (q >> 1)) * 512 + boff;
      union { u32 u[4]; bf16x8 v; } bu;
      bu.u[0] = __hip_atomic_load(p + 0, __ATOMIC_RELAXED, __HIP_MEMORY_SCOPE_AGENT);
      bu.u[1] = __hip_atomic_load(p + 1, __ATOMIC_RELAXED, __HIP_MEMORY_SCOPE_AGENT);
      bu.u[2] = __hip_atomic_load(p + 2, __ATOMIC_RELAXED, __HIP_MEMORY_SCOPE_AGENT);
      bu.u[3] = __hip_atomic_load(p + 3, __ATOMIC_RELAXED, __HIP_MEMORY_SCOPE_AGENT);
      if (kk & 1)
        acc1 = __builtin_amdgcn_mfma_f32_16x16x32_bf16(areg[kk], bu.v, acc1, 0, 0, 0);
      else
        acc0 = __builtin_amdgcn_mfma_f32_16x16x32_bf16(areg[kk], bu.v, acc0, 0, 0, 0);
    }
    f32x4 acc = acc0 + acc1;

    const float zi = acc[0] + bf2f((u16)(xpv.x & 0xffff));
    const float zf = acc[1] + bf2f((u16)(xpv.x >> 16));
    const float zg = acc[2] + bf2f((u16)(xpv.y & 0xffff));
    const float zo = acc[3] + bf2f((u16)(xpv.y >> 16));
    const float gi = fsigmoid(zi), gf = fsigmoid(zf);
    const float gg = ftanh(zg), go = fsigmoid(zo);
    c = gf * c + gi * gg;
    const float h = go * ftanh(c);

    hn[j * 1024 + b * 16 + hcl] = f2bf(h);
    if (it == 511) {
      out[(size_t)b * 1024 + hc] = h;
    } else {
      __syncthreads();   // drains all threads' stores (vmcnt) before barrier release
      if (tid == 0) {
        __threadfence();  // wbl2 -> data at LLC before flag
        __hip_atomic_store(flags + bq * 64 + j, it + 1,
                           __ATOMIC_RELAXED, __HIP_MEMORY_SCOPE_AGENT);
      }
    }
  }
}

// ---------------- launch ----------------
extern "C" void kernel_launch(void* const* d_in, const int* in_sizes, int n_in,
                              void* d_out, int out_size, void* d_ws, size_t ws_size,
                              hipStream_t stream) {
  const float* x  = (const float*)d_in[0];
  const float* Ui = (const float*)d_in[1];
  const float* Vi = (const float*)d_in[2];
  const float* bi = (const float*)d_in[3];
  const float* Uf = (const float*)d_in[4];
  const float* Vf = (const float*)d_in[5];
  const float* bf_ = (const float*)d_in[6];
  const float* Uc = (const float*)d_in[7];
  const float* Vc = (const float*)d_in[8];
  const float* bc = (const float*)d_in[9];
  const float* Uo = (const float*)d_in[10];
  const float* Vo = (const float*)d_in[11];
  const float* bo = (const float*)d_in[12];

  char* ws = (char*)d_ws;
  // layout: flags[256] @0 (1KB) | hbuf 2x128KB @1KB | xb 64MB @1MB |
  //         UbT 8MB @65MB | bb 16KB @73MB | xp 255.5MB @73MB+64KB  (~345MB total)
  int* flags = (int*)ws;
  u16* hbuf  = (u16*)(ws + 1024);
  u16* xb    = (u16*)(ws + (size_t)(1 << 20));
  u16* UbT   = (u16*)(ws + (size_t)(1 << 20) + ((size_t)64 << 20));
  float* bb  = (float*)(ws + (size_t)(1 << 20) + ((size_t)72 << 20));
  u16* xp    = (u16*)(ws + (size_t)(1 << 20) + ((size_t)72 << 20) + (1 << 16));

  conv_x<<<4096, 256, 0, stream>>>(x, xb);
  conv_u<<<1024, 256, 0, stream>>>(Ui, Uf, Uc, Uo, UbT);
  conv_b<<<16, 256, 0, stream>>>(bi, bf_, bc, bo, bb);
  init_ws<<<64, 256, 0, stream>>>(hbuf, flags);
  gemm_xproj<<<8192, 256, 0, stream>>>(xb, UbT, bb, xp);
  lstm_rec<<<256, 256, 0, stream>>>(Vi, Vf, Vc, Vo, xp, hbuf, flags, (float*)d_out);
}

// Round 2
// 2481.309 us; speedup vs baseline: 6.0000x; 6.0000x over previous
//
#include <hip/hip_runtime.h>
#include <stdint.h>

typedef unsigned short u16;
typedef unsigned int   u32;
typedef __bf16 bf16x8 __attribute__((ext_vector_type(8)));
typedef float  f32x4  __attribute__((ext_vector_type(4)));
typedef u16    u16x8  __attribute__((ext_vector_type(8)));
typedef u32    u32x4  __attribute__((ext_vector_type(4)));

#define TBROWS 32704   // 511 * 64 valid (t,b) rows

__device__ __forceinline__ u16 f2bf(float f) {
  union { float f; u32 u; } v; v.f = f;
  u32 r = v.u + 0x7FFFu + ((v.u >> 16) & 1u);   // RNE
  return (u16)(r >> 16);
}
__device__ __forceinline__ float bf2f(u16 h) {
  union { u32 u; float f; } v; v.u = ((u32)h) << 16;
  return v.f;
}
__device__ __forceinline__ float fsigmoid(float x) {
  return 1.0f / (1.0f + exp2f(-1.44269504f * x));
}
__device__ __forceinline__ float ftanh(float x) {
  return 2.0f / (1.0f + exp2f(-2.88539008f * x)) - 1.0f;
}

// ---------------- conversions ----------------

// x f32 [64][512][1024] -> bf16 same layout
__global__ __launch_bounds__(256) void conv_x(const float* __restrict__ x,
                                              u16* __restrict__ xb) {
  const int n4 = (64 * 512 * 1024) / 4;
  const float4* xv = (const float4*)x;
  for (int i = blockIdx.x * 256 + threadIdx.x; i < n4; i += 4096 * 256) {
    float4 v = xv[i];
    uint2 o;
    o.x = (u32)f2bf(v.x) | ((u32)f2bf(v.y) << 16);
    o.y = (u32)f2bf(v.z) | ((u32)f2bf(v.w) << 16);
    *(uint2*)(xb + (size_t)i * 4) = o;
  }
}

// Build UbT bf16 [4096][1024]: UbT[n][k] = U_g[k][hc], n = hc*4 + g (gate-interleaved)
__global__ __launch_bounds__(256) void conv_u(const float* __restrict__ U0,
                                              const float* __restrict__ U1,
                                              const float* __restrict__ U2,
                                              const float* __restrict__ U3,
                                              u16* __restrict__ UbT) {
  __shared__ float tile[64][65];
  const int bid = blockIdx.x;
  const int g = bid >> 8, kt = (bid >> 4) & 15, ht = bid & 15;
  const float* U = (g == 0) ? U0 : (g == 1) ? U1 : (g == 2) ? U2 : U3;
  const int t = threadIdx.x;
  const int c = t & 63, r0 = t >> 6;
#pragma unroll
  for (int rr = 0; rr < 64; rr += 4)
    tile[rr + r0][c] = U[(size_t)(kt * 64 + rr + r0) * 1024 + ht * 64 + c];
  __syncthreads();
  const int hcl = t >> 2, ks = t & 3;
  const int n = (ht * 64 + hcl) * 4 + g;
  u16x8 o0, o1;
#pragma unroll
  for (int ii = 0; ii < 8; ++ii) o0[ii] = f2bf(tile[ks * 16 + ii][hcl]);
#pragma unroll
  for (int ii = 0; ii < 8; ++ii) o1[ii] = f2bf(tile[ks * 16 + 8 + ii][hcl]);
  size_t base = (size_t)n * 1024 + kt * 64 + ks * 16;
  *(u16x8*)(UbT + base) = o0;
  *(u16x8*)(UbT + base + 8) = o1;
}

// bb f32 [4096] gate-interleaved: bb[hc*4+g] = b_g[hc]
__global__ __launch_bounds__(256) void conv_b(const float* __restrict__ b0,
                                              const float* __restrict__ b1,
                                              const float* __restrict__ b2,
                                              const float* __restrict__ b3,
                                              float* __restrict__ bb) {
  int n = blockIdx.x * 256 + threadIdx.x;
  if (n < 4096) {
    int g = n & 3, hc = n >> 2;
    const float* B = (g == 0) ? b0 : (g == 1) ? b1 : (g == 2) ? b2 : b3;
    bb[n] = B[hc];
  }
}

// zero h state buffer 0 and flags (re-run every call -> replay-safe)
__global__ __launch_bounds__(256) void init_ws(u16* hbuf, int* flags) {
  int i = blockIdx.x * 256 + threadIdx.x;     // 16384 threads
  if (i < 256) flags[i] = 0;
  u32* hz = (u32*)hbuf;
  for (int k = i; k < 32768; k += 16384) hz[k] = 0;
}

// ---------------- phase 1: x_proj GEMM ----------------
// Computes xp[hc][tb][g] = sum_k UbT[hc*4+g][k] * xb[tb][k] + bb  (bf16 out)
__global__ __launch_bounds__(256, 2) void gemm_xproj(const u16* __restrict__ xb,
                                                     const u16* __restrict__ UbT,
                                                     const float* __restrict__ bb,
                                                     u16* __restrict__ xp) {
  __shared__ __align__(16) u16 As[128 * 32];
  __shared__ __align__(16) u16 Bs[128 * 32];
  const int tid = threadIdx.x;
  const int lane = tid & 63, w = tid >> 6;
  const int q = lane >> 4, r15 = lane & 15;
  const int nt = blockIdx.x & 31;        // M (n) tile
  const int tt = blockIdx.x >> 5;        // N (tb) tile
  const int n_base = nt * 128;
  const long long tb_base = (long long)tt * 128;
  const int mh = w & 1, nh = w >> 1;

  f32x4 acc[4][4];
#pragma unroll
  for (int a = 0; a < 4; ++a)
#pragma unroll
    for (int b2 = 0; b2 < 4; ++b2) acc[a][b2] = (f32x4){0.f, 0.f, 0.f, 0.f};

#pragma unroll 1
  for (int kb = 0; kb < 32; ++kb) {
    __syncthreads();
    const int k0 = kb * 32;
#pragma unroll
    for (int call = 0; call < 2; ++call) {
      const int chunk = call * 256 + w * 64 + lane;
      const int row = chunk >> 2, q4 = chunk & 3;
      const u16* ga = UbT + (size_t)(n_base + row) * 1024 + k0 + q4 * 8;
      __builtin_amdgcn_global_load_lds(
          (const __attribute__((address_space(1))) void*)ga,
          (__attribute__((address_space(3))) void*)(As + (call * 256 + w * 64) * 8),
          16, 0, 0);
      long long tbr = tb_base + row;
      if (tbr > TBROWS - 1) tbr = TBROWS - 1;
      const int xbrow = ((int)tbr & 63) * 512 + ((int)tbr >> 6);  // (b,t) -> x row
      const u16* gb = xb + (size_t)xbrow * 1024 + k0 + q4 * 8;
      __builtin_amdgcn_global_load_lds(
          (const __attribute__((address_space(1))) void*)gb,
          (__attribute__((address_space(3))) void*)(Bs + (call * 256 + w * 64) * 8),
          16, 0, 0);
    }
    __syncthreads();
    bf16x8 af[4], bfr[4];
#pragma unroll
    for (int m = 0; m < 4; ++m)
      af[m] = *(const bf16x8*)(As + ((mh * 64 + m * 16 + r15) * 32 + q * 8));
#pragma unroll
    for (int n2 = 0; n2 < 4; ++n2)
      bfr[n2] = *(const bf16x8*)(Bs + ((nh * 64 + n2 * 16 + r15) * 32 + q * 8));
#pragma unroll
    for (int m = 0; m < 4; ++m)
#pragma unroll
      for (int n2 = 0; n2 < 4; ++n2)
        acc[m][n2] = __builtin_amdgcn_mfma_f32_16x16x32_bf16(af[m], bfr[n2],
                                                             acc[m][n2], 0, 0, 0);
  }
#pragma unroll
  for (int m = 0; m < 4; ++m) {
    const int nrow = n_base + mh * 64 + m * 16 + q * 4;
    const float4 bias = *(const float4*)(bb + nrow);
    const long long hcb = (long long)(nrow >> 2) * TBROWS;
#pragma unroll
    for (int n2 = 0; n2 < 4; ++n2) {
      const long long tb = tb_base + nh * 64 + n2 * 16 + r15;
      if (tb < TBROWS) {
        const f32x4 v = acc[m][n2];
        uint2 pk;
        pk.x = (u32)f2bf(v[0] + bias.x) | ((u32)f2bf(v[1] + bias.y) << 16);
        pk.y = (u32)f2bf(v[2] + bias.z) | ((u32)f2bf(v[3] + bias.w) << 16);
        *(uint2*)(xp + (hcb + tb) * 4) = pk;
      }
    }
  }
}

// ---------------- phase 2: persistent recurrence ----------------
// 256 blocks = 64 hc-blocks x 4 batch-quarters; 4 waves/block, K-split.
// Wave w owns K in [w*256,(w+1)*256) for all 64 z-rows; cross-wave reduce in LDS.
// V fragments fully register-resident (128 VGPR). h exchange via LLC-coherent
// sc0/sc1 loads-stores + per-producer flags. No cache-maintenance ops.
__global__ __launch_bounds__(256, 1) void lstm_rec(
    const float* __restrict__ V0, const float* __restrict__ V1,
    const float* __restrict__ V2, const float* __restrict__ V3,
    const u16* __restrict__ xp, u16* hbuf, int* flags, float* __restrict__ out) {
  __shared__ __align__(16) f32x4 part[4][4][64];   // [wave][tile][lane]
  const int tid = threadIdx.x;
  const int lane = tid & 63;
  const int w = tid >> 6;          // wave = K-quarter
  const int q = lane >> 4;
  const int r15 = lane & 15;
  const int j = blockIdx.x & 63;   // hc block (16 hidden units)
  const int bq = blockIdx.x >> 6;  // batch quarter (16 batches)
  const int b = bq * 16 + r15;

  // ---- A fragments (reg-resident): areg[t][kkl]
  // A[zrow = t*16 + r15][k = w*256 + kkl*32 + q*8 + jj],  zrow -> (hc,gate)
  const int gA = r15 & 3;
  const float* Vm = (gA == 0) ? V0 : (gA == 1) ? V1 : (gA == 2) ? V2 : V3;
  bf16x8 areg[4][8];
#pragma unroll
  for (int t = 0; t < 4; ++t) {
    const int hcA = j * 16 + t * 4 + (r15 >> 2);
    const float* Vcol = Vm + hcA;
#pragma unroll
    for (int kkl = 0; kkl < 8; ++kkl) {
      union { bf16x8 v; u16 s[8]; } au;
      const int k0 = w * 256 + kkl * 32 + q * 8;
#pragma unroll
      for (int jj = 0; jj < 8; ++jj)
        au.s[jj] = f2bf(Vcol[(size_t)(k0 + jj) * 1024]);
      areg[t][kkl] = au.v;
    }
  }

  // gate-owner identity of this lane (tile w): (b, hc), 4 gates in regs
  const int hcl = w * 4 + q;
  const int hc = j * 16 + hcl;
  const long long xpbase = (long long)hc * TBROWS * 4;
  // h-load lane offset (elements) within an h buffer
  const int laneoff = (w * 16 + (q >> 1)) * 1024 + b * 16 + (q & 1) * 8;
  const int* fp = flags + bq * 64 + w * 16 + (lane & 15);
  float c = 0.0f;

#pragma unroll 1
  for (int it = 0; it < 512; ++it) {
    // xp prefetch (independent of flags) — hides HBM latency under the poll
    const long long tb = (long long)(it < 511 ? it : 510) * 64 + b;
    const uint2 xpv = *(const uint2*)(xp + xpbase + tb * 4);

    if (it > 0) {
      while (__hip_atomic_load(fp, __ATOMIC_RELAXED, __HIP_MEMORY_SCOPE_AGENT) < it) {}
    }
    const u16* hp = hbuf + (size_t)(it & 1) * 65536;
    u16* hn = hbuf + (size_t)((it + 1) & 1) * 65536;

    // coherent vectorized h loads (LLC): 8 x 16B per lane
    const u16* hpl = hp + laneoff;
    u32x4 hb[8];
#pragma unroll
    for (int kkl = 0; kkl < 8; ++kkl)
      asm volatile("global_load_dwordx4 %0, %1, off sc0 sc1"
                   : "=v"(hb[kkl]) : "v"(hpl + kkl * 2048) : "memory");
    asm volatile("s_waitcnt vmcnt(0)" ::: "memory");
    __builtin_amdgcn_sched_barrier(0);

    f32x4 acc[4];
#pragma unroll
    for (int t = 0; t < 4; ++t) acc[t] = (f32x4){0.f, 0.f, 0.f, 0.f};
#pragma unroll
    for (int kkl = 0; kkl < 8; ++kkl) {
      union { u32x4 u; bf16x8 v; } bu; bu.u = hb[kkl];
#pragma unroll
      for (int t = 0; t < 4; ++t)
        acc[t] = __builtin_amdgcn_mfma_f32_16x16x32_bf16(areg[t][kkl], bu.v,
                                                         acc[t], 0, 0, 0);
    }

    // cross-wave K-reduction via LDS
#pragma unroll
    for (int t = 0; t < 4; ++t) part[w][t][lane] = acc[t];
    __syncthreads();
    f32x4 z4 = part[0][w][lane];
#pragma unroll
    for (int pw = 1; pw < 4; ++pw) z4 += part[pw][w][lane];

    const float zi = z4[0] + bf2f((u16)(xpv.x & 0xffff));
    const float zf = z4[1] + bf2f((u16)(xpv.x >> 16));
    const float zg = z4[2] + bf2f((u16)(xpv.y & 0xffff));
    const float zo = z4[3] + bf2f((u16)(xpv.y >> 16));
    const float gi = fsigmoid(zi), gf = fsigmoid(zf);
    const float gg = ftanh(zg), go = fsigmoid(zo);
    c = gf * c + gi * gg;
    const float h = go * ftanh(c);

    if (it == 511) {
      out[(size_t)b * 1024 + hc] = h;
    } else {
      // write-through h store -> LLC, then drain, barrier, release flag
      const u32 hv = (u32)f2bf(h);
      u16* hnp = hn + j * 1024 + b * 16 + hcl;
      asm volatile("global_store_short %0, %1, off sc0 sc1"
                   :: "v"(hnp), "v"(hv) : "memory");
      asm volatile("s_waitcnt vmcnt(0)" ::: "memory");
      __syncthreads();
      if (tid == 0)
        __hip_atomic_store(flags + bq * 64 + j, it + 1,
                           __ATOMIC_RELAXED, __HIP_MEMORY_SCOPE_AGENT);
    }
  }
}

// ---------------- launch ----------------
extern "C" void kernel_launch(void* const* d_in, const int* in_sizes, int n_in,
                              void* d_out, int out_size, void* d_ws, size_t ws_size,
                              hipStream_t stream) {
  const float* x  = (const float*)d_in[0];
  const float* Ui = (const float*)d_in[1];
  const float* Vi = (const float*)d_in[2];
  const float* bi = (const float*)d_in[3];
  const float* Uf = (const float*)d_in[4];
  const float* Vf = (const float*)d_in[5];
  const float* bf_ = (const float*)d_in[6];
  const float* Uc = (const float*)d_in[7];
  const float* Vc = (const float*)d_in[8];
  const float* bc = (const float*)d_in[9];
  const float* Uo = (const float*)d_in[10];
  const float* Vo = (const float*)d_in[11];
  const float* bo = (const float*)d_in[12];

  char* ws = (char*)d_ws;
  int* flags = (int*)ws;
  u16* hbuf  = (u16*)(ws + 1024);
  u16* xb    = (u16*)(ws + (size_t)(1 << 20));
  u16* UbT   = (u16*)(ws + (size_t)(1 << 20) + ((size_t)64 << 20));
  float* bb  = (float*)(ws + (size_t)(1 << 20) + ((size_t)72 << 20));
  u16* xp    = (u16*)(ws + (size_t)(1 << 20) + ((size_t)72 << 20) + (1 << 16));

  conv_x<<<4096, 256, 0, stream>>>(x, xb);
  conv_u<<<1024, 256, 0, stream>>>(Ui, Uf, Uc, Uo, UbT);
  conv_b<<<16, 256, 0, stream>>>(bi, bf_, bc, bo, bb);
  init_ws<<<64, 256, 0, stream>>>(hbuf, flags);
  gemm_xproj<<<8192, 256, 0, stream>>>(xb, UbT, bb, xp);
  lstm_rec<<<256, 256, 0, stream>>>(Vi, Vf, Vc, Vo, xp, hbuf, flags, (float*)d_out);
}